// Round 11
// baseline (19.142 us; speedup 1.0000x reference)
//
#include <hip/hip_runtime.h>
#include <math.h>

#define BATCH 128
#define N_IN 2048
#define N_OUT 1024
#define MAXK 40
#define BCAP 64
#define TEMP 0.1f
#define INV_TEMP 10.0f
#define NEG_FILL -1.0e9f
#define WLO -0.1875f
#define WHI 0.1875f
#define BINSCALE 682.6666666f  // 256 / (WHI - WLO)

__device__ __forceinline__ unsigned int f2key(float f) {
    unsigned int b = __float_as_uint(f);
    return (b & 0x80000000u) ? ~b : (b | 0x80000000u);
}
__device__ __forceinline__ float key2f(unsigned int u) {
    unsigned int b = (u & 0x80000000u) ? (u & 0x7FFFFFFFu) : ~u;
    return __uint_as_float(b);
}

// K1, grid = BATCH: exact lower-median of x row b (256-bin exact select,
// radix fallback), gate, publish TRANSPOSED gxT[idx][b] so K2's per-batch
// gathers are coalesced.
__global__ __launch_bounds__(256) void k_med(const float* __restrict__ x,
                                             float* __restrict__ gxT) {
    __shared__ unsigned int hist[256];
    __shared__ unsigned int wsum4[4];
    __shared__ unsigned int sel[2];
    __shared__ float sbin[BCAP];
    __shared__ int s_nb;
    __shared__ float s_med;

    const int tid = threadIdx.x;
    const int lane = tid & 63;
    const int wwid = tid >> 6;
    const int b = (int)blockIdx.x;

    const float4* xr = (const float4*)(x + (size_t)b * N_IN);
    float4 va = xr[tid], vb = xr[tid + 256];
    float vals[8] = {va.x, va.y, va.z, va.w, vb.x, vb.y, vb.z, vb.w};

    hist[tid] = 0;
    if (tid == 0) s_nb = 0;
    __syncthreads();

    // pass 1: count below window; 256-bin histogram of in-window values
    int cb = 0;
#pragma unroll
    for (int j = 0; j < 8; ++j) {
        float v = vals[j];
        cb += (v < WLO) ? 1 : 0;
        if (v >= WLO && v < WHI) {
            int bin = (int)((v - WLO) * BINSCALE);
            bin = (bin > 255) ? 255 : bin;
            atomicAdd(&hist[bin], 1u);
        }
    }
    int sb = cb;
#pragma unroll
    for (int off = 1; off < 64; off <<= 1) sb += __shfl_xor(sb, off, 64);
    if (lane == 0) wsum4[wwid] = (unsigned int)sb;
    __syncthreads();
    const int c_lo = (int)(wsum4[0] + wsum4[1] + wsum4[2] + wsum4[3]);
    const int R = (N_IN - 1) / 2 - c_lo;  // lower-median rank in window

    // inclusive scan of the 256-bin histogram
    unsigned int hv = hist[tid];
    unsigned int sv = hv;
#pragma unroll
    for (int off = 1; off < 64; off <<= 1) {
        unsigned int t = __shfl_up(sv, off, 64);
        if (lane >= off) sv += t;
    }
    __syncthreads();  // protect wsum4 reuse
    if (lane == 63) wsum4[wwid] = sv;
    if (tid == 0) sel[0] = 0xFFFFFFFFu;
    __syncthreads();
    unsigned int base = 0;
    for (int ww = 0; ww < wwid; ++ww) base += wsum4[ww];
    const unsigned int incl = sv + base;
    const unsigned int excl = incl - hv;
    const int n_c = (int)(wsum4[0] + wsum4[1] + wsum4[2] + wsum4[3]);
    if (R >= 0 && R < n_c && (unsigned int)R >= excl && (unsigned int)R < incl) {
        sel[0] = (unsigned int)tid;       // target bin
        sel[1] = (unsigned int)R - excl;  // rank within bin
    }
    __syncthreads();

    bool fast_ok = (R >= 0 && R < n_c && sel[0] != 0xFFFFFFFFu);
    if (fast_ok) {
        const int B = (int)sel[0];
        const int r2 = (int)sel[1];
#pragma unroll
        for (int j = 0; j < 8; ++j) {  // pass 2: compact target bin (~1-3 elems)
            float v = vals[j];
            if (v >= WLO && v < WHI) {
                int bin = (int)((v - WLO) * BINSCALE);
                bin = (bin > 255) ? 255 : bin;
                if (bin == B) {
                    int p = atomicAdd(&s_nb, 1);
                    if (p < BCAP) sbin[p] = v;
                }
            }
        }
        __syncthreads();
        const int nb = s_nb;
        if (nb <= BCAP) {
            if (tid < nb) {
                float v = sbin[tid];
                int nlt = 0, neq = 0;
                for (int j = 0; j < nb; ++j) {
                    float u = sbin[j];
                    nlt += (u < v) ? 1 : 0;
                    neq += (u == v) ? 1 : 0;
                }
                if (nlt <= r2 && r2 < nlt + neq) s_med = v;  // ties agree
            }
        } else {
            fast_ok = false;
        }
        __syncthreads();
    }
    if (!fast_ok) {
        // exact 4-pass radix select fallback (exactness never data-dependent)
        unsigned int prefix = 0;
        unsigned int k = (N_IN - 1) / 2;
        for (int pos = 24; pos >= 0; pos -= 8) {
            hist[tid] = 0;
            __syncthreads();
            const unsigned int hmask = (pos == 24) ? 0u : (0xFFFFFFFFu << (pos + 8));
#pragma unroll
            for (int j = 0; j < 8; ++j) {
                unsigned int u = f2key(vals[j]);
                if ((u & hmask) == (prefix & hmask))
                    atomicAdd(&hist[(u >> pos) & 0xFFu], 1u);
            }
            __syncthreads();
            unsigned int v = hist[tid];
            unsigned int s2 = v;
#pragma unroll
            for (int off = 1; off < 64; off <<= 1) {
                unsigned int t = __shfl_up(s2, off, 64);
                if (lane >= off) s2 += t;
            }
            if (lane == 63) wsum4[wwid] = s2;
            __syncthreads();
            unsigned int bs = 0;
            for (int ww = 0; ww < wwid; ++ww) bs += wsum4[ww];
            const unsigned int inc2 = s2 + bs;
            const unsigned int exc2 = inc2 - v;
            if (k >= exc2 && k < inc2) {
                sel[0] = (unsigned int)tid;
                sel[1] = k - exc2;
            }
            __syncthreads();
            prefix |= sel[0] << pos;
            k = sel[1];
            __syncthreads();
        }
        if (tid == 0) s_med = key2f(prefix);
        __syncthreads();
    }
    const float med = s_med;

    // gate + transposed publish (L2 merges the column scatter across blocks)
#pragma unroll
    for (int j = 0; j < 8; ++j) {
        const int idx = (j < 4) ? 4 * tid + j : 1024 + 4 * tid + (j - 4);
        const float v = vals[j];
        gxT[(size_t)idx * BATCH + b] = (fabsf(v - med) < 1.0f) ? v : 0.0f;
    }
}

// K2, grid = N_OUT/2: block handles outputs {2op, 2op+1} for ALL 128 batches.
// Reads only the 2 mask rows, compacts indices via dual-row shfl-scan,
// gathers the ~15 active weights per row, then online LSE with coalesced
// gxT[idx*128+b] gathers (tid&127 = b).
__global__ __launch_bounds__(256) void k_clse(const float* __restrict__ w,
                                              const float* __restrict__ msk,
                                              const float* __restrict__ gxT,
                                              float* __restrict__ out) {
    __shared__ unsigned int wsum4[4];
    __shared__ int sidx[2][MAXK];
    __shared__ float swv[2][MAXK];

    const int tid = threadIdx.x;
    const int lane = tid & 63;
    const int wwid = tid >> 6;
    const int o0 = (int)blockIdx.x * 2;

    const float4* m0 = (const float4*)(msk + (size_t)o0 * N_IN);
    const float4* m1 = (const float4*)(msk + (size_t)(o0 + 1) * N_IN);
    float4 m0a = m0[tid], m0b = m0[tid + 256];
    float4 m1a = m1[tid], m1b = m1[tid + 256];
    float mv0[8] = {m0a.x, m0a.y, m0a.z, m0a.w, m0b.x, m0b.y, m0b.z, m0b.w};
    float mv1[8] = {m1a.x, m1a.y, m1a.z, m1a.w, m1b.x, m1b.y, m1b.z, m1b.w};

    int c0 = 0, c1 = 0;
#pragma unroll
    for (int j = 0; j < 8; ++j) {
        c0 += (mv0[j] != 0.0f) ? 1 : 0;
        c1 += (mv1[j] != 0.0f) ? 1 : 0;
    }
    int packed = (c0 << 16) | c1;
    int sv = packed;
#pragma unroll
    for (int off = 1; off < 64; off <<= 1) {
        int t = __shfl_up(sv, off, 64);
        if (lane >= off) sv += t;
    }
    if (lane == 63) wsum4[wwid] = (unsigned int)sv;
    __syncthreads();
    int base = 0;
    for (int ww = 0; ww < wwid; ++ww) base += (int)wsum4[ww];
    const int excl = base + sv - packed;
    const int tot = (int)(wsum4[0] + wsum4[1] + wsum4[2] + wsum4[3]);
    const int ct0 = tot >> 16;
    const int ct1 = tot & 0xFFFF;

    int p0 = (excl >> 16) & 0xFFFF;
    int p1 = excl & 0xFFFF;
#pragma unroll
    for (int j = 0; j < 8; ++j) {
        const int idx = (j < 4) ? 4 * tid + j : 1024 + 4 * tid + (j - 4);
        if (mv0[j] != 0.0f) {
            if (p0 < MAXK) sidx[0][p0] = idx;
            ++p0;
        }
        if (mv1[j] != 0.0f) {
            if (p1 < MAXK) sidx[1][p1] = idx;
            ++p1;
        }
    }
    __syncthreads();

    // gather only the active weights (~15 of 2048 per row)
    const int cc0 = (ct0 < MAXK) ? ct0 : MAXK;
    const int cc1 = (ct1 < MAXK) ? ct1 : MAXK;
    if (tid < cc0) swv[0][tid] = w[(size_t)o0 * N_IN + sidx[0][tid]];
    else if (tid >= 64 && tid - 64 < cc1)
        swv[1][tid - 64] = w[(size_t)(o0 + 1) * N_IN + sidx[1][tid - 64]];
    __syncthreads();

    // online LSE: tid<128 -> (b=tid, o0); tid>=128 -> (b=tid-128, o0+1)
    const int oSel = tid >> 7;
    const int o = o0 + oSel;
    const int b = tid & 127;
    const int c = oSel ? ct1 : ct0;

    float res;
    if (c == 0) {
        res = NEG_FILL;  // T*(-1e10 + log 2048) rounds to -1e9 in f32
    } else if (c <= MAXK) {
        int idx = sidx[oSel][0];  // wave-uniform -> LDS broadcast
        float m = (gxT[(size_t)idx * BATCH + b] + swv[oSel][0]) * INV_TEMP;
        float s = 1.0f;
        for (int j = 1; j < c; ++j) {
            idx = sidx[oSel][j];
            float v = (gxT[(size_t)idx * BATCH + b] + swv[oSel][j]) * INV_TEMP;
            float mn = fmaxf(m, v);
            s = s * __expf(m - mn) + __expf(v - mn);
            m = mn;
        }
        res = TEMP * (m + __logf(s));
    } else {
        // overflow fallback (statistically unreachable): dense masked pass
        const float* mr = msk + (size_t)o * N_IN;
        const float* wr = w + (size_t)o * N_IN;
        float m = -INFINITY, s = 0.0f;
        for (int i = 0; i < N_IN; ++i) {
            if (mr[i] != 0.0f) {
                float v = (gxT[(size_t)i * BATCH + b] + wr[i]) * INV_TEMP;
                float mn = fmaxf(m, v);
                s = s * __expf(m - mn) + __expf(v - mn);
                m = mn;
            }
        }
        res = TEMP * (m + __logf(s));
    }
    out[(size_t)b * N_OUT + o] = res;
}

extern "C" void kernel_launch(void* const* d_in, const int* in_sizes, int n_in,
                              void* d_out, int out_size, void* d_ws, size_t ws_size,
                              hipStream_t stream) {
    const float* x = (const float*)d_in[0];
    const float* w = (const float*)d_in[1];
    const float* msk = (const float*)d_in[2];
    float* out = (float*)d_out;

    float* gxT = (float*)d_ws;  // N_IN * BATCH floats (1 MB), transposed gated x

    hipLaunchKernelGGL(k_med, dim3(BATCH), dim3(256), 0, stream, x, gxT);
    hipLaunchKernelGGL(k_clse, dim3(N_OUT / 2), dim3(256), 0, stream,
                       w, msk, gxT, out);
}